// Round 1
// baseline (608.177 us; speedup 1.0000x reference)
//
#include <hip/hip_runtime.h>
#include <hip/hip_bf16.h>
#include <math.h>

#define DIN   2048
#define DOUT  128
#define BHALF 4096
#define NTOT  8192

// ---------------------------------------------------------------------------
// Kernel A: zn[8192][128] = normalize(relu(z) @ W.T + b), fused.
// grid 256 x 256 threads; 32 rows/block. Also zeroes d_out (block 0).
// LDS tiles stored k-major with XOR swizzle so the transpose-store is
// bank-conflict-free and compute reads stay vectorized float4.
// ---------------------------------------------------------------------------
__global__ __launch_bounds__(256) void proj_norm_kernel(
    const float* __restrict__ zi, const float* __restrict__ zj,
    const float* __restrict__ W,  const float* __restrict__ bvec,
    float* __restrict__ zn, float* __restrict__ out)
{
    if (blockIdx.x == 0 && threadIdx.x == 0) out[0] = 0.0f;

    // element (k, r) at word k*32 + (r ^ (((k>>2)&7)<<2))
    __shared__ float Zt[32 * 32];
    // element (k, c) at word k*128 + (c ^ (((k>>2)&7)<<2))
    __shared__ float Wt[32 * 128];

    const int t    = threadIdx.x;
    const int ty   = t >> 5;   // 0..7  -> rows ty*4..+3
    const int tx   = t & 31;   // cols tx*4..+3
    const int row0 = blockIdx.x * 32;
    const float* zsrc = (row0 < BHALF) ? zi : zj;
    const int zr0     = (row0 < BHALF) ? row0 : row0 - BHALF;

    float acc[4][4];
    #pragma unroll
    for (int i = 0; i < 4; i++)
        #pragma unroll
        for (int j = 0; j < 4; j++) acc[i][j] = 0.f;

    // swizzled read word-offsets, u = k>>2 in 0..7 (compile-time indexed)
    int zoff[8], woff[8];
    #pragma unroll
    for (int u = 0; u < 8; u++) {
        zoff[u] = (ty * 4) ^ (u << 2);
        woff[u] = (tx * 4) ^ (u << 2);
    }

    for (int k0 = 0; k0 < DIN; k0 += 32) {
        // stage Z tile: 32 rows x 32 k = 256 float4, 1/thread, relu fused
        {
            int r = t >> 3, s = t & 7;
            float4 v = *(const float4*)(zsrc + (size_t)(zr0 + r) * DIN + k0 + s * 4);
            v.x = fmaxf(v.x, 0.f); v.y = fmaxf(v.y, 0.f);
            v.z = fmaxf(v.z, 0.f); v.w = fmaxf(v.w, 0.f);
            int rr = r ^ (s << 2);
            Zt[(4 * s + 0) * 32 + rr] = v.x;
            Zt[(4 * s + 1) * 32 + rr] = v.y;
            Zt[(4 * s + 2) * 32 + rr] = v.z;
            Zt[(4 * s + 3) * 32 + rr] = v.w;
        }
        // stage W tile: 128 cols x 32 k = 1024 float4, 4/thread
        #pragma unroll
        for (int l = 0; l < 4; l++) {
            int f = t + l * 256;
            int c = f >> 3, s = f & 7;
            float4 v = *(const float4*)(W + (size_t)c * DIN + k0 + s * 4);
            int cc = c ^ (s << 2);
            Wt[(4 * s + 0) * 128 + cc] = v.x;
            Wt[(4 * s + 1) * 128 + cc] = v.y;
            Wt[(4 * s + 2) * 128 + cc] = v.z;
            Wt[(4 * s + 3) * 128 + cc] = v.w;
        }
        __syncthreads();
        #pragma unroll
        for (int k = 0; k < 32; k++) {
            const int u = k >> 2;
            float4 zv = *(const float4*)&Zt[k * 32  + zoff[u]];
            float4 wv = *(const float4*)&Wt[k * 128 + woff[u]];
            float zr[4] = {zv.x, zv.y, zv.z, zv.w};
            #pragma unroll
            for (int i = 0; i < 4; i++) {
                acc[i][0] = fmaf(zr[i], wv.x, acc[i][0]);
                acc[i][1] = fmaf(zr[i], wv.y, acc[i][1]);
                acc[i][2] = fmaf(zr[i], wv.z, acc[i][2]);
                acc[i][3] = fmaf(zr[i], wv.w, acc[i][3]);
            }
        }
        __syncthreads();
    }

    // bias + row sum-of-squares (reduce across the 32 tx lanes) + normalize
    float4 bb = *(const float4*)(bvec + tx * 4);
    float ssq[4];
    #pragma unroll
    for (int i = 0; i < 4; i++) {
        acc[i][0] += bb.x; acc[i][1] += bb.y; acc[i][2] += bb.z; acc[i][3] += bb.w;
        ssq[i] = acc[i][0]*acc[i][0] + acc[i][1]*acc[i][1]
               + acc[i][2]*acc[i][2] + acc[i][3]*acc[i][3];
    }
    #pragma unroll
    for (int m = 1; m < 32; m <<= 1) {
        #pragma unroll
        for (int i = 0; i < 4; i++) ssq[i] += __shfl_xor(ssq[i], m);
    }
    #pragma unroll
    for (int i = 0; i < 4; i++) {
        float inv = 1.0f / fmaxf(sqrtf(ssq[i]), 1e-8f);
        float4 o = make_float4(acc[i][0]*inv, acc[i][1]*inv, acc[i][2]*inv, acc[i][3]*inv);
        *(float4*)(zn + (size_t)(row0 + ty * 4 + i) * DOUT + tx * 4) = o;
    }
}

// ---------------------------------------------------------------------------
// Kernel B: per row i, partial sum over a 4096-col j-range of exp(2*zn_i.zn_j)
// (skipping j==i), plus capture of the positive-pair logit.
// grid 512 = 256 row-groups (32 rows) x 2 j-splits; 256 threads.
// ---------------------------------------------------------------------------
__global__ __launch_bounds__(256) void sim_kernel(
    const float* __restrict__ zn, float* __restrict__ Spart, float* __restrict__ P)
{
    // element (k, r) at word k*32 + (r ^ (((k>>2)&15)<<1))
    __shared__ float It[128 * 32];
    // element (k, c) at word k*64 + (c ^ (((k>>2)&7)<<2))
    __shared__ float Jt[128 * 64];

    const int t      = threadIdx.x;
    const int ty     = t >> 4;   // 0..15 -> rows ty*2, ty*2+1
    const int tx     = t & 15;   // cols tx*4..+3
    const int rg     = blockIdx.x >> 1;
    const int sp     = blockIdx.x & 1;
    const int row0   = rg * 32;
    const int j0base = sp * 4096;

    // stage It once: 32 rows x 128 k = 1024 float4, 4/thread
    #pragma unroll
    for (int l = 0; l < 4; l++) {
        int f = t + l * 256;
        int r = f >> 5, s = f & 31;
        float4 v = *(const float4*)(zn + (size_t)(row0 + r) * DOUT + s * 4);
        int rr = r ^ ((s & 15) << 1);
        It[(4 * s + 0) * 32 + rr] = v.x;
        It[(4 * s + 1) * 32 + rr] = v.y;
        It[(4 * s + 2) * 32 + rr] = v.z;
        It[(4 * s + 3) * 32 + rr] = v.w;
    }

    int itoff[16], jtoff[8];
    #pragma unroll
    for (int u = 0; u < 16; u++) itoff[u] = (ty * 2) ^ (u << 1);
    #pragma unroll
    for (int u = 0; u < 8;  u++) jtoff[u] = (tx * 4) ^ (u << 2);

    const int gr0 = row0 + ty * 2, gr1 = gr0 + 1;
    const int pc0 = (gr0 + BHALF) & (NTOT - 1);
    const int pc1 = (gr1 + BHALF) & (NTOT - 1);
    float sexp0 = 0.f, sexp1 = 0.f, pos0 = 0.f, pos1 = 0.f;

    for (int jt = 0; jt < 4096; jt += 64) {
        const int j0 = j0base + jt;
        __syncthreads();
        // stage Jt: 64 cols x 128 k = 2048 float4, 8/thread
        #pragma unroll
        for (int l = 0; l < 8; l++) {
            int f = t + l * 256;
            int c = f >> 5, s = f & 31;
            float4 v = *(const float4*)(zn + (size_t)(j0 + c) * DOUT + s * 4);
            int cc = c ^ ((s & 7) << 2);
            Jt[(4 * s + 0) * 64 + cc] = v.x;
            Jt[(4 * s + 1) * 64 + cc] = v.y;
            Jt[(4 * s + 2) * 64 + cc] = v.z;
            Jt[(4 * s + 3) * 64 + cc] = v.w;
        }
        __syncthreads();

        float d[2][4];
        #pragma unroll
        for (int i = 0; i < 2; i++)
            #pragma unroll
            for (int j = 0; j < 4; j++) d[i][j] = 0.f;

        #pragma unroll
        for (int k = 0; k < 128; k++) {   // full unroll: itoff/jtoff idx compile-time
            const int u = k >> 2;
            float2 a  = *(const float2*)&It[k * 32 + itoff[u & 15]];
            float4 b4 = *(const float4*)&Jt[k * 64 + jtoff[u & 7]];
            d[0][0] = fmaf(a.x, b4.x, d[0][0]);
            d[0][1] = fmaf(a.x, b4.y, d[0][1]);
            d[0][2] = fmaf(a.x, b4.z, d[0][2]);
            d[0][3] = fmaf(a.x, b4.w, d[0][3]);
            d[1][0] = fmaf(a.y, b4.x, d[1][0]);
            d[1][1] = fmaf(a.y, b4.y, d[1][1]);
            d[1][2] = fmaf(a.y, b4.z, d[1][2]);
            d[1][3] = fmaf(a.y, b4.w, d[1][3]);
        }

        #pragma unroll
        for (int j = 0; j < 4; j++) {
            int gc = j0 + tx * 4 + j;
            float s0 = 2.f * d[0][j], s1 = 2.f * d[1][j];
            float e0 = __expf(s0),    e1 = __expf(s1);
            if (gc != gr0) sexp0 += e0;   // sim <= 2, so no max-subtraction needed
            if (gc != gr1) sexp1 += e1;
            if (gc == pc0) pos0 = s0;
            if (gc == pc1) pos1 = s1;
        }
    }

    // reduce across the 16 tx lanes (same ty = 16 consecutive lanes)
    #pragma unroll
    for (int m = 1; m < 16; m <<= 1) {
        sexp0 += __shfl_xor(sexp0, m);
        sexp1 += __shfl_xor(sexp1, m);
        pos0  += __shfl_xor(pos0,  m);
        pos1  += __shfl_xor(pos1,  m);
    }
    if (tx == 0) {
        Spart[sp * NTOT + gr0] = sexp0;
        Spart[sp * NTOT + gr1] = sexp1;
        if ((pc0 >> 12) == sp) P[gr0] = pos0;  // pos col lives in exactly one split
        if ((pc1 >> 12) == sp) P[gr1] = pos1;
    }
}

// ---------------------------------------------------------------------------
// Kernel C: loss = mean_i( log(S0[i]+S1[i]) - P[i] )
// ---------------------------------------------------------------------------
__global__ __launch_bounds__(256) void loss_kernel(
    const float* __restrict__ Spart, const float* __restrict__ P,
    float* __restrict__ out)
{
    int i = blockIdx.x * 256 + threadIdx.x;
    float v = logf(Spart[i] + Spart[NTOT + i]) - P[i];
    #pragma unroll
    for (int m = 1; m < 64; m <<= 1) v += __shfl_xor(v, m);
    __shared__ float red[4];
    if ((threadIdx.x & 63) == 0) red[threadIdx.x >> 6] = v;
    __syncthreads();
    if (threadIdx.x == 0) {
        float s = red[0] + red[1] + red[2] + red[3];
        atomicAdd(out, s * (1.0f / (float)NTOT));
    }
}

// ---------------------------------------------------------------------------
extern "C" void kernel_launch(void* const* d_in, const int* in_sizes, int n_in,
                              void* d_out, int out_size, void* d_ws, size_t ws_size,
                              hipStream_t stream) {
    const float* zi = (const float*)d_in[0];
    const float* zj = (const float*)d_in[1];
    const float* W  = (const float*)d_in[2];
    const float* bv = (const float*)d_in[3];
    float* out = (float*)d_out;

    float* zn    = (float*)d_ws;               // 8192*128 floats = 4 MB
    float* Spart = zn + (size_t)NTOT * DOUT;   // 2*8192 floats
    float* P     = Spart + 2 * NTOT;           // 8192 floats

    proj_norm_kernel<<<256, 256, 0, stream>>>(zi, zj, W, bv, zn, out);
    sim_kernel<<<512, 256, 0, stream>>>(zn, Spart, P);
    loss_kernel<<<NTOT / 256, 256, 0, stream>>>(Spart, P, out);
}

// Round 4
// 189.520 us; speedup vs baseline: 3.2090x; 3.2090x over previous
//
#include <hip/hip_runtime.h>
#include <math.h>

#define DIN    2048
#define DOUT   128
#define BHALF  4096
#define NTOT   8192
#define NSPLIT 8
#define JSPAN  1024   // NTOT / NSPLIT

typedef __bf16 bf16x8 __attribute__((ext_vector_type(8)));
typedef float  f32x4  __attribute__((ext_vector_type(4)));
typedef unsigned int u32x4 __attribute__((ext_vector_type(4)));

#define MFMA16 __builtin_amdgcn_mfma_f32_16x16x32_bf16

struct PackedPair { unsigned int h, l; };

__device__ __forceinline__ unsigned int bf16_rne(float f) {
    unsigned int u = __float_as_uint(f);
    return (u + 0x7fffu + ((u >> 16) & 1u)) >> 16;
}
__device__ __forceinline__ float bf16f(unsigned int h) {
    return __uint_as_float(h << 16);
}
// split a,b into packed-bf16 words: .h = hi parts, .l = lo parts
__device__ __forceinline__ PackedPair split2(float a, float b) {
    unsigned int h0 = bf16_rne(a), h1 = bf16_rne(b);
    unsigned int g0 = bf16_rne(a - bf16f(h0)), g1 = bf16_rne(b - bf16f(h1));
    PackedPair r;
    r.h = h0 | (h1 << 16);
    r.l = g0 | (g1 << 16);
    return r;
}

// Packed fragment layout for a matrix row r, feature k (K-tiles of 32):
//   group g = r>>4, ks = k>>5, lane = (r&15) | (((k>>3)&3)<<4), elem e = k&7
//   flat ushort index = ((g*KS + ks)*64 + lane)*8 + e
// The same packing serves MFMA A (index=row) and B (index=col) operands;
// any bijective k-permutation is self-consistent when both operands use it.

// ---------------------------------------------------------------------------
// Kernel 0: split W[128][2048] into packed bf16 hi/lo fragments. Zeroes out.
// ---------------------------------------------------------------------------
__global__ __launch_bounds__(256) void wsplit_kernel(
    const float* __restrict__ W,
    unsigned short* __restrict__ Whp, unsigned short* __restrict__ Wlp,
    float* __restrict__ out)
{
    int t = blockIdx.x * 256 + threadIdx.x;      // 32768 total
    if (t == 0) out[0] = 0.f;
    int l  = t & 63;
    int ks = (t >> 6) & 63;
    int g  = t >> 12;                            // 0..7
    int c  = g * 16 + (l & 15);
    int k0 = ks * 32 + ((l >> 4) << 3);
    const float* src = W + (size_t)c * DIN + k0;
    f32x4 v0 = *(const f32x4*)src;
    f32x4 v1 = *(const f32x4*)(src + 4);
    u32x4 hv, lv;
    PackedPair p0 = split2(v0[0], v0[1]);  hv[0] = p0.h; lv[0] = p0.l;
    PackedPair p1 = split2(v0[2], v0[3]);  hv[1] = p1.h; lv[1] = p1.l;
    PackedPair p2 = split2(v1[0], v1[1]);  hv[2] = p2.h; lv[2] = p2.l;
    PackedPair p3 = split2(v1[2], v1[3]);  hv[3] = p3.h; lv[3] = p3.l;
    size_t off = ((size_t)(g * 64 + ks) * 64 + l) * 8;
    *(u32x4*)(Whp + off) = hv;
    *(u32x4*)(Wlp + off) = lv;
}

// ---------------------------------------------------------------------------
// Kernel 1: h = relu(Z) @ W^T + b, rownorm, split+pack into Zhp/Zlp.
// 256 blocks x 512 thr (8 waves). Wave w owns K-chunk [w*256, +256).
// A fragments built on the fly from global fp32 Z (relu+split in regs).
// B fragments loaded straight from packed W (L2-resident, coalesced 1KB).
// Cross-wave reduce via 64KB LDS tree, then fused epilogue.
// ---------------------------------------------------------------------------
__global__ __launch_bounds__(512) void proj_kernel(
    const float* __restrict__ zi, const float* __restrict__ zj,
    const unsigned short* __restrict__ Whp, const unsigned short* __restrict__ Wlp,
    const float* __restrict__ bvec,
    unsigned short* __restrict__ Zhp, unsigned short* __restrict__ Zlp)
{
    __shared__ float Red[4][32][128];            // 64 KB
    const int t = threadIdx.x;
    const int w = t >> 6;                        // 0..7
    const int lane = t & 63;
    const int r15 = lane & 15, q = lane >> 4;    // q: k-subchunk 0..3
    const int row0 = blockIdx.x * 32;
    const float* zsrc = (row0 < BHALF) ? zi : zj;
    const int zr0 = (row0 < BHALF) ? row0 : row0 - BHALF;

    f32x4 acc[2][8];
    #pragma unroll
    for (int m = 0; m < 2; m++)
        #pragma unroll
        for (int g = 0; g < 8; g++) acc[m][g] = (f32x4){0.f, 0.f, 0.f, 0.f};

    for (int ks = w * 8; ks < w * 8 + 8; ks++) {
        const int k0 = ks * 32 + q * 8;
        bf16x8 ah[2], al[2];
        #pragma unroll
        for (int m = 0; m < 2; m++) {
            const float* s = zsrc + (size_t)(zr0 + m * 16 + r15) * DIN + k0;
            f32x4 v0 = *(const f32x4*)s;
            f32x4 v1 = *(const f32x4*)(s + 4);
            #pragma unroll
            for (int p = 0; p < 4; p++) {
                v0[p] = fmaxf(v0[p], 0.f);
                v1[p] = fmaxf(v1[p], 0.f);
            }
            u32x4 hv, lv;
            PackedPair p0 = split2(v0[0], v0[1]);  hv[0] = p0.h; lv[0] = p0.l;
            PackedPair p1 = split2(v0[2], v0[3]);  hv[1] = p1.h; lv[1] = p1.l;
            PackedPair p2 = split2(v1[0], v1[1]);  hv[2] = p2.h; lv[2] = p2.l;
            PackedPair p3 = split2(v1[2], v1[3]);  hv[3] = p3.h; lv[3] = p3.l;
            ah[m] = __builtin_bit_cast(bf16x8, hv);
            al[m] = __builtin_bit_cast(bf16x8, lv);
        }
        #pragma unroll
        for (int g = 0; g < 8; g++) {
            size_t bo = ((size_t)(g * 64 + ks) * 64 + lane) * 8;
            bf16x8 bh = __builtin_bit_cast(bf16x8, *(const u32x4*)(Whp + bo));
            bf16x8 bl = __builtin_bit_cast(bf16x8, *(const u32x4*)(Wlp + bo));
            #pragma unroll
            for (int m = 0; m < 2; m++) {
                acc[m][g] = MFMA16(ah[m], bh, acc[m][g], 0, 0, 0);
                acc[m][g] = MFMA16(ah[m], bl, acc[m][g], 0, 0, 0);
                acc[m][g] = MFMA16(al[m], bh, acc[m][g], 0, 0, 0);
            }
        }
    }

    // two-stage cross-wave reduce: waves 4-7 dump, waves 0-3 add + dump
    if (w >= 4) {
        #pragma unroll
        for (int m = 0; m < 2; m++)
            #pragma unroll
            for (int g = 0; g < 8; g++)
                #pragma unroll
                for (int r = 0; r < 4; r++)
                    Red[w - 4][m * 16 + q * 4 + r][g * 16 + r15] = acc[m][g][r];
    }
    __syncthreads();
    if (w < 4) {
        #pragma unroll
        for (int m = 0; m < 2; m++)
            #pragma unroll
            for (int g = 0; g < 8; g++)
                #pragma unroll
                for (int r = 0; r < 4; r++) {
                    int rr = m * 16 + q * 4 + r, cc = g * 16 + r15;
                    Red[w][rr][cc] += acc[m][g][r];
                }
    }
    __syncthreads();

    // epilogue: bias + norm + split + packed write. 512 thr: 2 rows each.
    const int ty = t >> 5;        // 0..15
    const int tx = t & 31;        // cols tx*4..+3
    const f32x4 bb = *(const f32x4*)(bvec + tx * 4);
    #pragma unroll
    for (int i = 0; i < 2; i++) {
        const int row = ty * 2 + i;
        f32x4 v = (f32x4){0.f, 0.f, 0.f, 0.f};
        #pragma unroll
        for (int ww = 0; ww < 4; ww++)
            v += *(const f32x4*)&Red[ww][row][tx * 4];
        v += bb;
        float ssq = v[0]*v[0] + v[1]*v[1] + v[2]*v[2] + v[3]*v[3];
        #pragma unroll
        for (int msk = 1; msk < 32; msk <<= 1) ssq += __shfl_xor(ssq, msk);
        const float inv = 1.f / fmaxf(sqrtf(ssq), 1e-8f);
        const int grow = row0 + row;
        const int gg = grow >> 4, rr = grow & 15;
        #pragma unroll
        for (int j = 0; j < 4; j++) {
            const int k = tx * 4 + j;
            float x = v[j] * inv;
            unsigned int h  = bf16_rne(x);
            unsigned int lo = bf16_rne(x - bf16f(h));
            size_t off = (((size_t)gg * 4 + (k >> 5)) * 64
                          + (rr | (((k >> 3) & 3) << 4))) * 8 + (k & 7);
            Zhp[off] = (unsigned short)h;
            Zlp[off] = (unsigned short)lo;
        }
    }
}

// ---------------------------------------------------------------------------
// Kernel 2: sim = (zn zn^T)/T with fused exp/mask/pos + row partial sums.
// grid 512 = 64 i-blocks (128 rows) x 8 j-splits (1024 cols); 256 thr/4 waves.
// Wave owns 32 i-rows; A frags (hi+lo, K=128) live in registers all kernel.
// 64-col j-tiles staged in 32KB LDS in packed layout (lane-contiguous 16B,
// conflict-free). 3 MFMAs per (m,jg,ks) for the hi/lo cross terms.
// ---------------------------------------------------------------------------
__global__ __launch_bounds__(256) void sim_kernel(
    const unsigned short* __restrict__ Zhp, const unsigned short* __restrict__ Zlp,
    float* __restrict__ Spart, float* __restrict__ P)
{
    __shared__ unsigned short Jt[16384];         // 32 KB, 32 chunks of 1KB
    const int t = threadIdx.x;
    const int w = t >> 6, lane = t & 63;
    const int r15 = lane & 15, rq = lane >> 4;
    const int iblk   = blockIdx.x >> 3;
    const int jsplit = blockIdx.x & 7;
    const int rowbase = iblk * 128 + w * 32;

    bf16x8 Ah[2][4], Al[2][4];
    #pragma unroll
    for (int m = 0; m < 2; m++) {
        const int gA = iblk * 8 + w * 2 + m;
        #pragma unroll
        for (int ks = 0; ks < 4; ks++) {
            size_t ao = (((size_t)gA * 4 + ks) * 64 + lane) * 8;
            Ah[m][ks] = __builtin_bit_cast(bf16x8, *(const u32x4*)(Zhp + ao));
            Al[m][ks] = __builtin_bit_cast(bf16x8, *(const u32x4*)(Zlp + ao));
        }
    }

    float rs[2][4], ps[2][4];
    #pragma unroll
    for (int m = 0; m < 2; m++)
        #pragma unroll
        for (int r = 0; r < 4; r++) { rs[m][r] = 0.f; ps[m][r] = 0.f; }

    for (int jt = 0; jt < JSPAN / 64; jt++) {
        const int j0 = jsplit * JSPAN + jt * 64;
        __syncthreads();
        // stage 64 cols x 128 k, hi+lo: 32 chunks x 1KB, 8 x 16B per thread
        #pragma unroll
        for (int rr = 0; rr < 8; rr++) {
            int flat = t + rr * 256;             // 0..2047
            int cid = flat >> 6, ll = flat & 63;
            int hl = cid >> 4, jg = (cid >> 2) & 3, ks = cid & 3;
            const unsigned short* src = hl ? Zlp : Zhp;
            size_t so = (((size_t)((j0 >> 4) + jg) * 4 + ks) * 64 + ll) * 8;
            *(u32x4*)&Jt[(size_t)flat * 8] = *(const u32x4*)(src + so);
        }
        __syncthreads();

        f32x4 acc[2][4];
        #pragma unroll
        for (int m = 0; m < 2; m++)
            #pragma unroll
            for (int jg = 0; jg < 4; jg++) acc[m][jg] = (f32x4){0.f,0.f,0.f,0.f};

        #pragma unroll
        for (int ks = 0; ks < 4; ks++) {
            #pragma unroll
            for (int jg = 0; jg < 4; jg++) {
                bf16x8 bh = __builtin_bit_cast(bf16x8,
                    *(const u32x4*)&Jt[((jg * 4 + ks) * 64 + lane) * 8]);
                bf16x8 bl = __builtin_bit_cast(bf16x8,
                    *(const u32x4*)&Jt[((jg * 4 + ks + 16) * 64 + lane) * 8]);
                #pragma unroll
                for (int m = 0; m < 2; m++) {
                    acc[m][jg] = MFMA16(Ah[m][ks], bh, acc[m][jg], 0, 0, 0);
                    acc[m][jg] = MFMA16(Ah[m][ks], bl, acc[m][jg], 0, 0, 0);
                    acc[m][jg] = MFMA16(Al[m][ks], bh, acc[m][jg], 0, 0, 0);
                }
            }
        }

        // fused epilogue: s=2*dot, self-mask, exp-accumulate, pos capture
        #pragma unroll
        for (int m = 0; m < 2; m++) {
            const int growb = rowbase + m * 16 + rq * 4;
            #pragma unroll
            for (int jg = 0; jg < 4; jg++) {
                const int gcol = j0 + jg * 16 + r15;
                #pragma unroll
                for (int r = 0; r < 4; r++) {
                    float s = 2.f * acc[m][jg][r];   // sim <= ~2: no max-sub needed
                    const int grow = growb + r;
                    float e = __expf(s);
                    if (gcol == grow) e = 0.f;
                    rs[m][r] += e;
                    if (gcol == (grow ^ BHALF)) ps[m][r] += s;
                }
            }
        }
    }

    #pragma unroll
    for (int m = 0; m < 2; m++)
        #pragma unroll
        for (int r = 0; r < 4; r++) {
            float a = rs[m][r], p = ps[m][r];
            #pragma unroll
            for (int msk = 1; msk < 16; msk <<= 1) {
                a += __shfl_xor(a, msk);
                p += __shfl_xor(p, msk);
            }
            if (r15 == 0) {
                const int grow = rowbase + m * 16 + rq * 4 + r;
                Spart[jsplit * NTOT + grow] = a;
                if (((grow ^ BHALF) >> 10) == jsplit) P[grow] = p;
            }
        }
}

// ---------------------------------------------------------------------------
// Kernel 3: loss = mean_i( log(sum_sp Spart[sp][i]) - P[i] )
// ---------------------------------------------------------------------------
__global__ __launch_bounds__(256) void loss_kernel(
    const float* __restrict__ Spart, const float* __restrict__ P,
    float* __restrict__ out)
{
    const int i = blockIdx.x * 256 + threadIdx.x;
    float ssum = 0.f;
    #pragma unroll
    for (int sp = 0; sp < NSPLIT; sp++) ssum += Spart[sp * NTOT + i];
    float v = logf(ssum) - P[i];
    #pragma unroll
    for (int msk = 1; msk < 64; msk <<= 1) v += __shfl_xor(v, msk);
    __shared__ float red[4];
    if ((threadIdx.x & 63) == 0) red[threadIdx.x >> 6] = v;
    __syncthreads();
    if (threadIdx.x == 0)
        atomicAdd(out, (red[0] + red[1] + red[2] + red[3]) * (1.f / (float)NTOT));
}

// ---------------------------------------------------------------------------
extern "C" void kernel_launch(void* const* d_in, const int* in_sizes, int n_in,
                              void* d_out, int out_size, void* d_ws, size_t ws_size,
                              hipStream_t stream) {
    const float* zi = (const float*)d_in[0];
    const float* zj = (const float*)d_in[1];
    const float* W  = (const float*)d_in[2];
    const float* bv = (const float*)d_in[3];
    float* out = (float*)d_out;

    char* ws = (char*)d_ws;
    unsigned short* Whp = (unsigned short*)(ws);                     // 512 KB
    unsigned short* Wlp = (unsigned short*)(ws + (512 << 10));       // 512 KB
    unsigned short* Zhp = (unsigned short*)(ws + (1024 << 10));      // 2 MB
    unsigned short* Zlp = (unsigned short*)(ws + (3072 << 10));      // 2 MB
    // Spart/P alias the W-packed region: W frags are dead once proj finishes.
    float* Spart = (float*)(ws);                                     // 256 KB
    float* P     = (float*)(ws + (256 << 10));                       // 32 KB

    wsplit_kernel<<<128, 256, 0, stream>>>(W, Whp, Wlp, out);
    proj_kernel<<<256, 512, 0, stream>>>(zi, zj, Whp, Wlp, bv, Zhp, Zlp);
    sim_kernel<<<512, 256, 0, stream>>>(Zhp, Zlp, Spart, P);
    loss_kernel<<<NTOT / 256, 256, 0, stream>>>(Spart, P, out);
}